// Round 8
// baseline (303.038 us; speedup 1.0000x reference)
//
#include <hip/hip_runtime.h>
#include <hip/hip_bf16.h>
#include <float.h>
#include <limits.h>

// Problem constants (fixed by reference setup_inputs)
#define BATCH 8
#define NN    4096
#define CC    256
#define KNN_K 4
#define NKE   (NN * KNN_K)

// R18 post-mortem: anchor reproduced (main 199us, total 258; occ 33.5, VGPR
// 64). Occupancy is the ground truth for true register allocation; R14-R16's
// occ=25% means their true VGPR >170 — "smaller" source, fatter codegen.
// R19: the only quantified loss left is PACKING: 1024 blocks at 3/CU = 1.33
// generations -> measured occ 33.5 vs 37.5 ideal (~11% under-packed tail).
// Fix: 3-way j-split -> 1536 blocks = exactly 2 generations of 3/CU.
// Hot loop/wave layout/insert/LDS byte-identical to R18; only launch
// geometry, the preamble range decode (nsplit, part, chunk window), and the
// epilogue sval stride change (18 cands/row rescored vs 12 — small term).
// Proven 2-way path retained as workspace fallback tier.
#define MTI  64
#define NJ   64
#define NC8  8     // per-lane packed top-k during scan
#define NM6  6     // per-(row,part) merged top-k, rescored in-kernel
#define BROW 264   // B-LDS ushort stride (256 + 8 pad) = 528 B

typedef __attribute__((ext_vector_type(8))) short  bf16x8;
typedef __attribute__((ext_vector_type(4))) float  f32x4;

// fp32 -> bf16 round-to-nearest-even (inputs finite)
__device__ __forceinline__ short f2bf(float f) {
    unsigned u = __float_as_uint(f);
    return (short)((u + 0x7FFFu + ((u >> 16) & 1u)) >> 16);
}

__device__ __forceinline__ unsigned umin32(unsigned a, unsigned b) { return a < b ? a : b; }
__device__ __forceinline__ unsigned umax32(unsigned a, unsigned b) { return a > b ? a : b; }

// branchless sorted-desc insert: t'[s] = max(t[s], min(t[s-1], k)); t'[0]=max(t[0],k)
__device__ __forceinline__ void pk_ins8(unsigned k, unsigned (&t)[NC8]) {
    #pragma unroll
    for (int s = NC8 - 1; s > 0; --s) t[s] = umax32(t[s], umin32(t[s - 1], k));
    t[0] = umax32(t[0], k);
}
__device__ __forceinline__ void pk_ins6(unsigned k, unsigned (&t)[NM6]) {
    #pragma unroll
    for (int s = NM6 - 1; s > 0; --s) t[s] = umax32(t[s], umin32(t[s - 1], k));
    t[0] = umax32(t[0], k);
}

// final-selection predicate matching jax.lax.top_k: value desc, ties -> smaller j
__device__ __forceinline__ bool knn_better(float v, int j, float v2, int j2) {
    return (v > v2) || (v == v2 && j < j2);
}
__device__ __forceinline__ void knn_insert4(float v, int j, float (&tv)[4], int (&tj)[4]) {
    if (knn_better(v, j, tv[3], tj[3])) {
        tv[3] = v; tj[3] = j;
        #pragma unroll
        for (int s = 3; s > 0; --s) {
            if (knn_better(tv[s], tj[s], tv[s - 1], tj[s - 1])) {
                float fv = tv[s]; tv[s] = tv[s - 1]; tv[s - 1] = fv;
                int   fj = tj[s]; tj[s] = tj[s - 1]; tj[s - 1] = fj;
            }
        }
    }
}

// ---------------------------------------------------------------------------
// Kernel 1: per-row inv-norm (+ optional normalized bf16 Xn to ws).
// ---------------------------------------------------------------------------
__global__ void knn_prep_kernel(const float* __restrict__ x, float* __restrict__ invn,
                                ushort* __restrict__ xn, int write_bf16) {
    const int row  = blockIdx.x * 4 + (threadIdx.x >> 6);
    const int lane = threadIdx.x & 63;
    const float4 v = *(const float4*)(x + (size_t)row * CC + lane * 4);
    float ss = v.x * v.x + v.y * v.y + v.z * v.z + v.w * v.w;
    #pragma unroll
    for (int off = 32; off > 0; off >>= 1) ss += __shfl_down(ss, off, 64);
    const float inv = 1.0f / sqrtf(__shfl(ss, 0, 64));
    if (lane == 0) invn[row] = inv;
    if (write_bf16) {
        short4 s4;
        s4.x = f2bf(v.x * inv); s4.y = f2bf(v.y * inv);
        s4.z = f2bf(v.z * inv); s4.w = f2bf(v.w * inv);
        *(short4*)(xn + (size_t)row * CC + lane * 4) = s4;
    }
}

// ---------------------------------------------------------------------------
// Kernel 2: 64 i-rows/block vs a j-range (1/nsplit of chunks; nsplit=0 ->
// full). Per 64-col chunk:
//   barA | pregs->Bsh | barB | issue next loads | 32 MFMA | packed inserts
// Epilogue: shfl-butterfly (16 lm-lanes) -> per-row packed top-6 -> in-kernel
// fp32 rescore (EXACT sequential-fmaf chain). Split mode writes scored
// (val,j) pairs to ws; full mode selects top-4 and writes outputs directly.
// ---------------------------------------------------------------------------
template<bool FROM_BF16>
__global__ __launch_bounds__(256, 3) void knn_main_kernel(
        const float* __restrict__ x, const float* __restrict__ invn,
        const ushort* __restrict__ xn, float* __restrict__ out,
        float* __restrict__ sval, int* __restrict__ sjid, int nsplit) {
    __shared__ __align__(16) ushort Bsh[NJ * BROW];   // 33792 B (only LDS)

    const int tid = threadIdx.x;
    const int b   = blockIdx.x & 7;          // batch -> XCD pinning
    const int t   = blockIdx.x >> 3;
    int it, part, c0, c1;
    if (nsplit) {                            // j-split decode (preamble-only)
        it   = t / nsplit;                   // i-tile 0..63
        part = t - it * nsplit;              // j-part 0..nsplit-1
        c0   = (64 * part) / nsplit;         // chunk window [c0, c1)
        c1   = (64 * (part + 1)) / nsplit;
    } else {
        it = t; part = 0; c0 = 0; c1 = 64;
    }
    const int i0    = it * MTI;
    const int jbase = c0 * NJ;
    const int nch   = c1 - c0;

    const float*  xb   = x    + (size_t)b * NN * CC;
    const ushort* xnb  = xn   + (size_t)b * NN * CC;
    const float*  invb = invn + (size_t)b * NN;

    const int w  = tid >> 6;                 // wave 0..3 (rows w*16..w*16+15)
    const int l  = tid & 63;
    const int lm = l & 15;                   // MFMA m/n lane
    const int q  = l >> 4;                   // quad 0..3

    // ---- A-frags in registers (32 VGPRs); A[m=lane&15][k=quad*8+j] ----
    bf16x8 afrag[8];
    const int gi = i0 + w * 16 + lm;
    if (FROM_BF16) {
        #pragma unroll
        for (int kt = 0; kt < 8; ++kt)
            afrag[kt] = *(const bf16x8*)(xnb + (size_t)gi * CC + kt * 32 + q * 8);
    } else {
        const float vi = invb[gi];
        #pragma unroll
        for (int kt = 0; kt < 8; ++kt) {
            const float* src = xb + (size_t)gi * CC + kt * 32 + q * 8;
            const float4 f0 = *(const float4*)(src);
            const float4 f1 = *(const float4*)(src + 4);
            bf16x8 a;
            a[0] = f2bf(f0.x * vi); a[1] = f2bf(f0.y * vi);
            a[2] = f2bf(f0.z * vi); a[3] = f2bf(f0.w * vi);
            a[4] = f2bf(f1.x * vi); a[5] = f2bf(f1.y * vi);
            a[6] = f2bf(f1.z * vi); a[7] = f2bf(f1.w * vi);
            afrag[kt] = a;
        }
    }

    // per-lane packed top-8, one list per owned row (reg 0..3 = rows q*4+reg)
    unsigned cl[4][NC8];
    #pragma unroll
    for (int r = 0; r < 4; ++r)
        #pragma unroll
        for (int s = 0; s < NC8; ++s) cl[r][s] = 0u;

    // staging ids: 16B granule; rows s_r0+8*lp, 32 granules/row
    const int s_gc = tid & 31;
    const int s_r0 = tid >> 5;
    bf16x8 pregs[8];
    if (FROM_BF16) {
        #pragma unroll
        for (int lp = 0; lp < 8; ++lp)
            pregs[lp] = *(const bf16x8*)(xnb + (size_t)(jbase + s_r0 + 8 * lp) * CC + s_gc * 8);
    }

    for (int jt = 0; jt < nch; ++jt) {
        const int j0 = jbase + jt * NJ;
        __syncthreads();                      // (A) prior kt-loop readers done
        if (FROM_BF16) {
            #pragma unroll
            for (int lp = 0; lp < 8; ++lp)
                *(bf16x8*)(Bsh + (s_r0 + 8 * lp) * BROW + s_gc * 8) = pregs[lp];
        } else {
            #pragma unroll
            for (int lp = 0; lp < 16; ++lp) {
                const int u2 = tid + 256 * lp;
                const int row = u2 >> 6, c4 = u2 & 63;
                const float sc = invb[j0 + row];
                const float4 v = *(const float4*)(xb + (size_t)(j0 + row) * CC + c4 * 4);
                short4 s4;
                s4.x = f2bf(v.x * sc); s4.y = f2bf(v.y * sc);
                s4.z = f2bf(v.z * sc); s4.w = f2bf(v.w * sc);
                *(short4*)(Bsh + row * BROW + c4 * 4) = s4;
            }
        }
        __syncthreads();                      // (B) Bsh ready
        // issue NEXT chunk's loads AFTER the barrier (stay in flight through
        // MFMA+insert; s_barrier would have forced vmcnt(0))
        if (FROM_BF16 && jt + 1 < nch) {
            const int jn = jbase + (jt + 1) * NJ;
            #pragma unroll
            for (int lp = 0; lp < 8; ++lp)
                pregs[lp] = *(const bf16x8*)(xnb + (size_t)(jn + s_r0 + 8 * lp) * CC + s_gc * 8);
        }

        f32x4 acc[4];
        #pragma unroll
        for (int ct = 0; ct < 4; ++ct) acc[ct] = (f32x4){0.f, 0.f, 0.f, 0.f};
        #pragma unroll
        for (int kt = 0; kt < 8; ++kt) {
            #pragma unroll
            for (int ct = 0; ct < 4; ++ct) {
                const bf16x8 bf = *(const bf16x8*)(Bsh + (ct * 16 + lm) * BROW + kt * 32 + q * 8);
                acc[ct] = __builtin_amdgcn_mfma_f32_16x16x32_bf16(afrag[kt], bf, acc[ct], 0, 0, 0);
            }
        }

        // ---- pack + branchless insert (no LDS, no divergence) ----
        // key = bits(sim+2.0) top-20 (monotone, ULP~3e-5); low-12 = 4095-j
        const bool dchunk = (j0 == i0);
        #pragma unroll
        for (int ct = 0; ct < 4; ++ct) {
            const int jg  = j0 + ct * 16 + lm;
            const unsigned ivj = (unsigned)(4095 - jg);
            #pragma unroll
            for (int r = 0; r < 4; ++r) {
                unsigned pk = (__float_as_uint(acc[ct][r] + 2.0f) & 0xFFFFF000u) | ivj;
                if (dchunk && (w * 16 + q * 4 + r) == (ct * 16 + lm)) pk = 0u;  // self
                pk_ins8(pk, cl[r]);
            }
        }
    }

    // ---- butterfly merge across the 16 lm-lanes -> per-row packed top-6 ----
    unsigned tm[4][NM6];
    #pragma unroll
    for (int r = 0; r < 4; ++r)
        #pragma unroll
        for (int s = 0; s < NM6; ++s) tm[r][s] = cl[r][s];   // top-6 of sorted top-8
    #pragma unroll
    for (int m = 1; m <= 8; m <<= 1) {
        #pragma unroll
        for (int r = 0; r < 4; ++r) {
            unsigned pin[NM6];
            #pragma unroll
            for (int s = 0; s < NM6; ++s)
                pin[s] = (unsigned)__shfl_xor((int)tm[r][s], m, 64);
            #pragma unroll
            for (int s = 0; s < NM6; ++s) pk_ins6(pin[s], tm[r]);
        }
    }

    // ---- stash per-row top-6 into LDS (Bsh reuse) for the rescore phase ----
    unsigned* cpk = (unsigned*)Bsh;              // [64][6] packed (1.5 KB)
    __syncthreads();                             // all kt-loop readers done
    if (lm == 0) {
        #pragma unroll
        for (int r = 0; r < 4; ++r) {
            const int rt = w * 16 + q * 4 + r;
            #pragma unroll
            for (int s = 0; s < NM6; ++s) cpk[rt * NM6 + s] = tm[r][s];
        }
    }
    __syncthreads();

    // ---- in-kernel fp32 rescore: EXACT sequential-fmaf chain ----
    // thread t: row = t&63, slot = t>>6; slots 0/1 do 2 cands, 2/3 do 1.
    const int rr   = tid & 63;
    const int slot = tid >> 6;
    const int ig   = i0 + rr;
    const float inv_i = invb[ig];
    const float* xi = xb + (size_t)ig * CC;
    const int ncand = (slot < 2) ? 2 : 1;
    const int cbase = (slot < 2) ? slot * 2 : 2 + slot;   // {0,1},{2,3},{4},{5}
    float rv[2]; int rj[2];
    for (int u = 0; u < ncand; ++u) {
        const int c  = cbase + u;
        const int jc = 4095 - (int)(cpk[rr * NM6 + c] & 0xFFFu);
        const float* xj = xb + (size_t)jc * CC;
        float d = 0.f;
        #pragma unroll 16
        for (int k4 = 0; k4 < 64; ++k4) {
            const float4 av = *(const float4*)(xi + k4 * 4);
            const float4 bv = *(const float4*)(xj + k4 * 4);
            d = fmaf(av.x, bv.x, d);
            d = fmaf(av.y, bv.y, d);
            d = fmaf(av.z, bv.z, d);
            d = fmaf(av.w, bv.w, d);
        }
        rv[u] = d * inv_i * invb[jc];
        rj[u] = jc;
    }

    if (nsplit) {
        // split mode: write scored pairs; select kernel finishes
        for (int u = 0; u < ncand; ++u) {
            const size_t o = ((size_t)(b * NN + ig) * nsplit + part) * NM6 + (cbase + u);
            sval[o] = rv[u];
            sjid[o] = rj[u];
        }
        return;
    }

    // full-j mode: select top-4 of 6 in-block
    float* cvl = (float*)(Bsh + 4096);           // [64][6] fp32 vals
    for (int u = 0; u < ncand; ++u) cvl[rr * NM6 + (cbase + u)] = rv[u];
    __syncthreads();
    if (tid < MTI) {
        const int r = tid, ig2 = i0 + r;
        float fv[4]; int fj[4];
        #pragma unroll
        for (int s = 0; s < 4; ++s) { fv[s] = -INFINITY; fj[s] = INT_MAX; }
        for (int c = 0; c < NM6; ++c) {
            const int jc = 4095 - (int)(cpk[r * NM6 + c] & 0xFFFu);
            knn_insert4(cvl[r * NM6 + c], jc, fv, fj);
        }
        float* o_src = out + (size_t)b * 2 * NKE;
        float* o_tgt = o_src + NKE;
        float* o_w   = out + (size_t)BATCH * 2 * NKE + (size_t)b * NKE;
        #pragma unroll
        for (int s = 0; s < 4; ++s) {
            o_src[ig2 * KNN_K + s] = (float)ig2;
            o_tgt[ig2 * KNN_K + s] = (float)fj[s];
            o_w[ig2 * KNN_K + s]   = fv[s];
        }
    }
}

// ---------------------------------------------------------------------------
// Kernel 3 (split mode): top-4 of nsplit*6 pre-scored (val,j) pairs per row.
// ---------------------------------------------------------------------------
__global__ __launch_bounds__(256) void knn_select_kernel(
        const float* __restrict__ sval, const int* __restrict__ sjid,
        float* __restrict__ out, int nsplit) {
    const int row_g = blockIdx.x * 256 + threadIdx.x;   // 0..32767
    const int bb = row_g >> 12, ig = row_g & (NN - 1);
    float fv[4]; int fj[4];
    #pragma unroll
    for (int s = 0; s < 4; ++s) { fv[s] = -INFINITY; fj[s] = INT_MAX; }
    const size_t base = (size_t)row_g * nsplit * NM6;
    for (int c = 0; c < nsplit * NM6; ++c)
        knn_insert4(sval[base + c], sjid[base + c], fv, fj);
    float* o_src = out + (size_t)bb * 2 * NKE;
    float* o_tgt = o_src + NKE;
    float* o_w   = out + (size_t)BATCH * 2 * NKE + (size_t)bb * NKE;
    #pragma unroll
    for (int s = 0; s < 4; ++s) {
        o_src[ig * KNN_K + s] = (float)ig;
        o_tgt[ig * KNN_K + s] = (float)fj[s];
        o_w[ig * KNN_K + s]   = fv[s];
    }
}

extern "C" void kernel_launch(void* const* d_in, const int* in_sizes, int n_in,
                              void* d_out, int out_size, void* d_ws, size_t ws_size,
                              hipStream_t stream) {
    const float* x    = (const float*)d_in[0];
    float*       out  = (float*)d_out;
    float*       invn = (float*)d_ws;                                   // 128 KB
    ushort*      xn   = (ushort*)((char*)d_ws + 131072);                // 16.78 MB
    char*        p2   = (char*)d_ws + 131072 + (size_t)BATCH * NN * CC * sizeof(ushort);
    const size_t need_xn = 131072 + (size_t)BATCH * NN * CC * sizeof(ushort);
    const size_t need_2  = need_xn + (size_t)BATCH * NN * 2 * NM6 * 8;  // +3.15 MB
    const size_t need_3  = need_xn + (size_t)BATCH * NN * 3 * NM6 * 8;  // +4.72 MB

    int nsplit = 0;
    if      (ws_size >= need_3) nsplit = 3;   // 1536 blocks = exactly 6/CU
    else if (ws_size >= need_2) nsplit = 2;   // proven 2-way fallback

    if (nsplit) {
        float* sval = (float*)p2;
        int*   sjid = (int*)(p2 + (size_t)BATCH * NN * nsplit * NM6 * sizeof(float));
        knn_prep_kernel<<<(BATCH * NN) / 4, 256, 0, stream>>>(x, invn, xn, 1);
        knn_main_kernel<true><<<BATCH * (NN / MTI) * nsplit, 256, 0, stream>>>(
            x, invn, xn, out, sval, sjid, nsplit);
        knn_select_kernel<<<(BATCH * NN) / 256, 256, 0, stream>>>(sval, sjid, out, nsplit);
    } else if (ws_size >= need_xn) {
        knn_prep_kernel<<<(BATCH * NN) / 4, 256, 0, stream>>>(x, invn, xn, 1);
        knn_main_kernel<true><<<BATCH * (NN / MTI), 256, 0, stream>>>(
            x, invn, xn, out, nullptr, nullptr, 0);
    } else {
        knn_prep_kernel<<<(BATCH * NN) / 4, 256, 0, stream>>>(x, invn, xn, 0);
        knn_main_kernel<false><<<BATCH * (NN / MTI), 256, 0, stream>>>(
            x, invn, xn, out, nullptr, nullptr, 0);
    }
}

// Round 9
// 273.803 us; speedup vs baseline: 1.1068x; 1.1068x over previous
//
#include <hip/hip_runtime.h>
#include <hip/hip_bf16.h>
#include <float.h>
#include <limits.h>

// Problem constants (fixed by reference setup_inputs)
#define BATCH 8
#define NN    4096
#define CC    256
#define KNN_K 4
#define NKE   (NN * KNN_K)

// R19 post-mortem: 3-way j-split regressed (main 199->246us/dispatch; occ
// 34 not 37.5; FETCH 62->108MB). Packing theory falsified — per-block
// fixed cost + L2 locality loss dominate; nsplit=2 is the proven geometry.
// R20: final catalog lever — s_setprio(1) around the MFMA+ds_read cluster.
// CU hosts 3 INDEPENDENT blocks at different phases (attn-like, +4-7% case,
// not lockstep-GEMM null): compute-phase waves can pre-empt staging-phase
// waves of co-resident blocks. SOPP-only: no operands, no regalloc risk
// (vs R14's asm). Everything else byte-identical to the R18 anchor
// (main 199us, total 258). Pre-commit: <=193 keep; 193-205 null -> revert
// and conclude latency-structural ceiling; >205 revert.
#define MTI  64
#define NJ   64
#define NC8  8     // per-lane packed top-k during scan
#define NM6  6     // per-(row,half) merged top-k, rescored in-kernel
#define BROW 264   // B-LDS ushort stride (256 + 8 pad) = 528 B

typedef __attribute__((ext_vector_type(8))) short  bf16x8;
typedef __attribute__((ext_vector_type(4))) float  f32x4;

// fp32 -> bf16 round-to-nearest-even (inputs finite)
__device__ __forceinline__ short f2bf(float f) {
    unsigned u = __float_as_uint(f);
    return (short)((u + 0x7FFFu + ((u >> 16) & 1u)) >> 16);
}

__device__ __forceinline__ unsigned umin32(unsigned a, unsigned b) { return a < b ? a : b; }
__device__ __forceinline__ unsigned umax32(unsigned a, unsigned b) { return a > b ? a : b; }

// branchless sorted-desc insert: t'[s] = max(t[s], min(t[s-1], k)); t'[0]=max(t[0],k)
__device__ __forceinline__ void pk_ins8(unsigned k, unsigned (&t)[NC8]) {
    #pragma unroll
    for (int s = NC8 - 1; s > 0; --s) t[s] = umax32(t[s], umin32(t[s - 1], k));
    t[0] = umax32(t[0], k);
}
__device__ __forceinline__ void pk_ins6(unsigned k, unsigned (&t)[NM6]) {
    #pragma unroll
    for (int s = NM6 - 1; s > 0; --s) t[s] = umax32(t[s], umin32(t[s - 1], k));
    t[0] = umax32(t[0], k);
}

// final-selection predicate matching jax.lax.top_k: value desc, ties -> smaller j
__device__ __forceinline__ bool knn_better(float v, int j, float v2, int j2) {
    return (v > v2) || (v == v2 && j < j2);
}
__device__ __forceinline__ void knn_insert4(float v, int j, float (&tv)[4], int (&tj)[4]) {
    if (knn_better(v, j, tv[3], tj[3])) {
        tv[3] = v; tj[3] = j;
        #pragma unroll
        for (int s = 3; s > 0; --s) {
            if (knn_better(tv[s], tj[s], tv[s - 1], tj[s - 1])) {
                float fv = tv[s]; tv[s] = tv[s - 1]; tv[s - 1] = fv;
                int   fj = tj[s]; tj[s] = tj[s - 1]; tj[s - 1] = fj;
            }
        }
    }
}

// ---------------------------------------------------------------------------
// Kernel 1: per-row inv-norm (+ optional normalized bf16 Xn to ws).
// ---------------------------------------------------------------------------
__global__ void knn_prep_kernel(const float* __restrict__ x, float* __restrict__ invn,
                                ushort* __restrict__ xn, int write_bf16) {
    const int row  = blockIdx.x * 4 + (threadIdx.x >> 6);
    const int lane = threadIdx.x & 63;
    const float4 v = *(const float4*)(x + (size_t)row * CC + lane * 4);
    float ss = v.x * v.x + v.y * v.y + v.z * v.z + v.w * v.w;
    #pragma unroll
    for (int off = 32; off > 0; off >>= 1) ss += __shfl_down(ss, off, 64);
    const float inv = 1.0f / sqrtf(__shfl(ss, 0, 64));
    if (lane == 0) invn[row] = inv;
    if (write_bf16) {
        short4 s4;
        s4.x = f2bf(v.x * inv); s4.y = f2bf(v.y * inv);
        s4.z = f2bf(v.z * inv); s4.w = f2bf(v.w * inv);
        *(short4*)(xn + (size_t)row * CC + lane * 4) = s4;
    }
}

// ---------------------------------------------------------------------------
// Kernel 2: 64 i-rows/block vs a j-range (half or full). Per 64-col chunk:
//   barA | pregs->Bsh | barB | issue next loads | 32 MFMA | packed inserts
// Epilogue: shfl-butterfly (16 lm-lanes) -> per-row packed top-6 -> in-kernel
// fp32 rescore (EXACT sequential-fmaf chain). Split mode writes scored
// (val,j) pairs to ws; full mode selects top-4 and writes outputs directly.
// ---------------------------------------------------------------------------
template<bool FROM_BF16>
__global__ __launch_bounds__(256, 3) void knn_main_kernel(
        const float* __restrict__ x, const float* __restrict__ invn,
        const ushort* __restrict__ xn, float* __restrict__ out,
        float* __restrict__ sval, int* __restrict__ sjid, int nh2) {
    __shared__ __align__(16) ushort Bsh[NJ * BROW];   // 33792 B (only LDS)

    const int tid = threadIdx.x;
    const int b   = blockIdx.x & 7;          // batch -> XCD pinning
    const int t   = blockIdx.x >> 3;
    const int it   = nh2 ? (t >> 1) : t;     // i-tile 0..63
    const int half = nh2 ? (t & 1)  : 0;     // j-half
    const int i0   = it * MTI;
    const int jbase = half * (NN / 2);
    const int nch   = nh2 ? (NN / NJ / 2) : (NN / NJ);

    const float*  xb   = x    + (size_t)b * NN * CC;
    const ushort* xnb  = xn   + (size_t)b * NN * CC;
    const float*  invb = invn + (size_t)b * NN;

    const int w  = tid >> 6;                 // wave 0..3 (rows w*16..w*16+15)
    const int l  = tid & 63;
    const int lm = l & 15;                   // MFMA m/n lane
    const int q  = l >> 4;                   // quad 0..3

    // ---- A-frags in registers (32 VGPRs); A[m=lane&15][k=quad*8+j] ----
    bf16x8 afrag[8];
    const int gi = i0 + w * 16 + lm;
    if (FROM_BF16) {
        #pragma unroll
        for (int kt = 0; kt < 8; ++kt)
            afrag[kt] = *(const bf16x8*)(xnb + (size_t)gi * CC + kt * 32 + q * 8);
    } else {
        const float vi = invb[gi];
        #pragma unroll
        for (int kt = 0; kt < 8; ++kt) {
            const float* src = xb + (size_t)gi * CC + kt * 32 + q * 8;
            const float4 f0 = *(const float4*)(src);
            const float4 f1 = *(const float4*)(src + 4);
            bf16x8 a;
            a[0] = f2bf(f0.x * vi); a[1] = f2bf(f0.y * vi);
            a[2] = f2bf(f0.z * vi); a[3] = f2bf(f0.w * vi);
            a[4] = f2bf(f1.x * vi); a[5] = f2bf(f1.y * vi);
            a[6] = f2bf(f1.z * vi); a[7] = f2bf(f1.w * vi);
            afrag[kt] = a;
        }
    }

    // per-lane packed top-8, one list per owned row (reg 0..3 = rows q*4+reg)
    unsigned cl[4][NC8];
    #pragma unroll
    for (int r = 0; r < 4; ++r)
        #pragma unroll
        for (int s = 0; s < NC8; ++s) cl[r][s] = 0u;

    // staging ids: 16B granule; rows s_r0+8*lp, 32 granules/row
    const int s_gc = tid & 31;
    const int s_r0 = tid >> 5;
    bf16x8 pregs[8];
    if (FROM_BF16) {
        #pragma unroll
        for (int lp = 0; lp < 8; ++lp)
            pregs[lp] = *(const bf16x8*)(xnb + (size_t)(jbase + s_r0 + 8 * lp) * CC + s_gc * 8);
    }

    for (int jt = 0; jt < nch; ++jt) {
        const int j0 = jbase + jt * NJ;
        __syncthreads();                      // (A) prior kt-loop readers done
        if (FROM_BF16) {
            #pragma unroll
            for (int lp = 0; lp < 8; ++lp)
                *(bf16x8*)(Bsh + (s_r0 + 8 * lp) * BROW + s_gc * 8) = pregs[lp];
        } else {
            #pragma unroll
            for (int lp = 0; lp < 16; ++lp) {
                const int u2 = tid + 256 * lp;
                const int row = u2 >> 6, c4 = u2 & 63;
                const float sc = invb[j0 + row];
                const float4 v = *(const float4*)(xb + (size_t)(j0 + row) * CC + c4 * 4);
                short4 s4;
                s4.x = f2bf(v.x * sc); s4.y = f2bf(v.y * sc);
                s4.z = f2bf(v.z * sc); s4.w = f2bf(v.w * sc);
                *(short4*)(Bsh + row * BROW + c4 * 4) = s4;
            }
        }
        __syncthreads();                      // (B) Bsh ready
        // issue NEXT chunk's loads AFTER the barrier (stay in flight through
        // MFMA+insert; s_barrier would have forced vmcnt(0))
        if (FROM_BF16 && jt + 1 < nch) {
            const int jn = jbase + (jt + 1) * NJ;
            #pragma unroll
            for (int lp = 0; lp < 8; ++lp)
                pregs[lp] = *(const bf16x8*)(xnb + (size_t)(jn + s_r0 + 8 * lp) * CC + s_gc * 8);
        }

        f32x4 acc[4];
        #pragma unroll
        for (int ct = 0; ct < 4; ++ct) acc[ct] = (f32x4){0.f, 0.f, 0.f, 0.f};
        // T5: prioritize the compute cluster over co-resident blocks'
        // staging-phase waves (3 independent blocks/CU = phase diversity).
        __builtin_amdgcn_s_setprio(1);
        #pragma unroll
        for (int kt = 0; kt < 8; ++kt) {
            #pragma unroll
            for (int ct = 0; ct < 4; ++ct) {
                const bf16x8 bf = *(const bf16x8*)(Bsh + (ct * 16 + lm) * BROW + kt * 32 + q * 8);
                acc[ct] = __builtin_amdgcn_mfma_f32_16x16x32_bf16(afrag[kt], bf, acc[ct], 0, 0, 0);
            }
        }
        __builtin_amdgcn_s_setprio(0);

        // ---- pack + branchless insert (no LDS, no divergence) ----
        // key = bits(sim+2.0) top-20 (monotone, ULP~3e-5); low-12 = 4095-j
        const bool dchunk = (j0 == i0);
        #pragma unroll
        for (int ct = 0; ct < 4; ++ct) {
            const int jg  = j0 + ct * 16 + lm;
            const unsigned ivj = (unsigned)(4095 - jg);
            #pragma unroll
            for (int r = 0; r < 4; ++r) {
                unsigned pk = (__float_as_uint(acc[ct][r] + 2.0f) & 0xFFFFF000u) | ivj;
                if (dchunk && (w * 16 + q * 4 + r) == (ct * 16 + lm)) pk = 0u;  // self
                pk_ins8(pk, cl[r]);
            }
        }
    }

    // ---- butterfly merge across the 16 lm-lanes -> per-row packed top-6 ----
    unsigned tm[4][NM6];
    #pragma unroll
    for (int r = 0; r < 4; ++r)
        #pragma unroll
        for (int s = 0; s < NM6; ++s) tm[r][s] = cl[r][s];   // top-6 of sorted top-8
    #pragma unroll
    for (int m = 1; m <= 8; m <<= 1) {
        #pragma unroll
        for (int r = 0; r < 4; ++r) {
            unsigned pin[NM6];
            #pragma unroll
            for (int s = 0; s < NM6; ++s)
                pin[s] = (unsigned)__shfl_xor((int)tm[r][s], m, 64);
            #pragma unroll
            for (int s = 0; s < NM6; ++s) pk_ins6(pin[s], tm[r]);
        }
    }

    // ---- stash per-row top-6 into LDS (Bsh reuse) for the rescore phase ----
    unsigned* cpk = (unsigned*)Bsh;              // [64][6] packed (1.5 KB)
    __syncthreads();                             // all kt-loop readers done
    if (lm == 0) {
        #pragma unroll
        for (int r = 0; r < 4; ++r) {
            const int rt = w * 16 + q * 4 + r;
            #pragma unroll
            for (int s = 0; s < NM6; ++s) cpk[rt * NM6 + s] = tm[r][s];
        }
    }
    __syncthreads();

    // ---- in-kernel fp32 rescore: EXACT sequential-fmaf chain ----
    // thread t: row = t&63, slot = t>>6; slots 0/1 do 2 cands, 2/3 do 1.
    const int rr   = tid & 63;
    const int slot = tid >> 6;
    const int ig   = i0 + rr;
    const float inv_i = invb[ig];
    const float* xi = xb + (size_t)ig * CC;
    const int ncand = (slot < 2) ? 2 : 1;
    const int cbase = (slot < 2) ? slot * 2 : 2 + slot;   // {0,1},{2,3},{4},{5}
    float rv[2]; int rj[2];
    for (int u = 0; u < ncand; ++u) {
        const int c  = cbase + u;
        const int jc = 4095 - (int)(cpk[rr * NM6 + c] & 0xFFFu);
        const float* xj = xb + (size_t)jc * CC;
        float d = 0.f;
        #pragma unroll 16
        for (int k4 = 0; k4 < 64; ++k4) {
            const float4 av = *(const float4*)(xi + k4 * 4);
            const float4 bv = *(const float4*)(xj + k4 * 4);
            d = fmaf(av.x, bv.x, d);
            d = fmaf(av.y, bv.y, d);
            d = fmaf(av.z, bv.z, d);
            d = fmaf(av.w, bv.w, d);
        }
        rv[u] = d * inv_i * invb[jc];
        rj[u] = jc;
    }

    if (nh2) {
        // split mode: write scored pairs; select kernel finishes
        for (int u = 0; u < ncand; ++u) {
            const size_t o = ((size_t)(b * NN + ig) * 2 + half) * NM6 + (cbase + u);
            sval[o] = rv[u];
            sjid[o] = rj[u];
        }
        return;
    }

    // full-j mode: select top-4 of 6 in-block
    float* cvl = (float*)(Bsh + 4096);           // [64][6] fp32 vals
    for (int u = 0; u < ncand; ++u) cvl[rr * NM6 + (cbase + u)] = rv[u];
    __syncthreads();
    if (tid < MTI) {
        const int r = tid, ig2 = i0 + r;
        float fv[4]; int fj[4];
        #pragma unroll
        for (int s = 0; s < 4; ++s) { fv[s] = -INFINITY; fj[s] = INT_MAX; }
        for (int c = 0; c < NM6; ++c) {
            const int jc = 4095 - (int)(cpk[r * NM6 + c] & 0xFFFu);
            knn_insert4(cvl[r * NM6 + c], jc, fv, fj);
        }
        float* o_src = out + (size_t)b * 2 * NKE;
        float* o_tgt = o_src + NKE;
        float* o_w   = out + (size_t)BATCH * 2 * NKE + (size_t)b * NKE;
        #pragma unroll
        for (int s = 0; s < 4; ++s) {
            o_src[ig2 * KNN_K + s] = (float)ig2;
            o_tgt[ig2 * KNN_K + s] = (float)fj[s];
            o_w[ig2 * KNN_K + s]   = fv[s];
        }
    }
}

// ---------------------------------------------------------------------------
// Kernel 3 (split mode): top-4 of 12 pre-scored (val,j) pairs per row. 3MB.
// ---------------------------------------------------------------------------
__global__ __launch_bounds__(256) void knn_select_kernel(
        const float* __restrict__ sval, const int* __restrict__ sjid,
        float* __restrict__ out) {
    const int row_g = blockIdx.x * 256 + threadIdx.x;   // 0..32767
    const int bb = row_g >> 12, ig = row_g & (NN - 1);
    float fv[4]; int fj[4];
    #pragma unroll
    for (int s = 0; s < 4; ++s) { fv[s] = -INFINITY; fj[s] = INT_MAX; }
    const size_t base = (size_t)row_g * 2 * NM6;
    for (int c = 0; c < 2 * NM6; ++c)
        knn_insert4(sval[base + c], sjid[base + c], fv, fj);
    float* o_src = out + (size_t)bb * 2 * NKE;
    float* o_tgt = o_src + NKE;
    float* o_w   = out + (size_t)BATCH * 2 * NKE + (size_t)bb * NKE;
    #pragma unroll
    for (int s = 0; s < 4; ++s) {
        o_src[ig * KNN_K + s] = (float)ig;
        o_tgt[ig * KNN_K + s] = (float)fj[s];
        o_w[ig * KNN_K + s]   = fv[s];
    }
}

extern "C" void kernel_launch(void* const* d_in, const int* in_sizes, int n_in,
                              void* d_out, int out_size, void* d_ws, size_t ws_size,
                              hipStream_t stream) {
    const float* x    = (const float*)d_in[0];
    float*       out  = (float*)d_out;
    float*       invn = (float*)d_ws;                                   // 128 KB
    ushort*      xn   = (ushort*)((char*)d_ws + 131072);                // 16.78 MB
    char*        p2   = (char*)d_ws + 131072 + (size_t)BATCH * NN * CC * sizeof(ushort);
    float*       sval = (float*)p2;                                     // 1.57 MB
    int*         sjid = (int*)(p2 + (size_t)BATCH * NN * 2 * NM6 * sizeof(float));
    const size_t need_xn  = 131072 + (size_t)BATCH * NN * CC * sizeof(ushort);
    const size_t need_all = need_xn + (size_t)BATCH * NN * 2 * NM6 * 8;

    if (ws_size >= need_all) {
        knn_prep_kernel<<<(BATCH * NN) / 4, 256, 0, stream>>>(x, invn, xn, 1);
        knn_main_kernel<true><<<BATCH * MTI * 2, 256, 0, stream>>>(x, invn, xn, out, sval, sjid, 1);
        knn_select_kernel<<<(BATCH * NN) / 256, 256, 0, stream>>>(sval, sjid, out);
    } else if (ws_size >= need_xn) {
        knn_prep_kernel<<<(BATCH * NN) / 4, 256, 0, stream>>>(x, invn, xn, 1);
        knn_main_kernel<true><<<BATCH * MTI, 256, 0, stream>>>(x, invn, xn, out, nullptr, nullptr, 0);
    } else {
        knn_prep_kernel<<<(BATCH * NN) / 4, 256, 0, stream>>>(x, invn, xn, 0);
        knn_main_kernel<false><<<BATCH * MTI, 256, 0, stream>>>(x, invn, xn, out, nullptr, nullptr, 0);
    }
}